// Round 1
// baseline (2105.425 us; speedup 1.0000x reference)
//
#include <hip/hip_runtime.h>

// LSTM 2-layer scan: N=1024 independent rows, T=2048 sequential steps.
// Block (256 thr, 4 waves) per batch row; lane quad = 4 gates of one hidden unit.
// W_hh1 row in registers; h1 double-buffered in LDS; 1 barrier/step.
// Layer 2 on a rotating wave, pipelined one step behind.

constexpr int H  = 51;
constexpr int TL = 2048;

__device__ __forceinline__ float rcpf(float x) { return __builtin_amdgcn_rcpf(x); }
__device__ __forceinline__ float sigf(float x) { return rcpf(1.0f + __expf(-x)); }
__device__ __forceinline__ float tanhfast(float x) {
    // 1 - 2/(e^{2x}+1); saturates correctly at +-inf
    return 1.0f - 2.0f * rcpf(__expf(x + x) + 1.0f);
}

template <int PAT>
__device__ __forceinline__ float quadb(float v) {
    // DPP quad_perm broadcast of quad-lane k (PAT = k*0x55), pure VALU
    return __int_as_float(__builtin_amdgcn_update_dpp(
        0, __float_as_int(v), PAT, 0xF, 0xF, true));
}

__device__ __forceinline__ void layer2_step(
    const float* __restrict__ hprev, int lane,
    const float (&w2)[4], const float (&wh2)[4], const float (&b2)[4],
    float* __restrict__ c2h2, float* __restrict__ out_ptr)
{
    const float hp = (lane < H) ? hprev[lane] : 0.0f;
    float p0 = w2[0] * hp, p1 = w2[1] * hp, p2 = w2[2] * hp, p3 = w2[3] * hp;
    #pragma unroll
    for (int m = 1; m <= 32; m <<= 1) {
        p0 += __shfl_xor(p0, m, 64);
        p1 += __shfl_xor(p1, m, 64);
        p2 += __shfl_xor(p2, m, 64);
        p3 += __shfl_xor(p3, m, 64);
    }
    const float c2 = c2h2[0], h2 = c2h2[1];
    const float a0 = fmaf(wh2[0], h2, p0) + b2[0];
    const float a1 = fmaf(wh2[1], h2, p1) + b2[1];
    const float a2 = fmaf(wh2[2], h2, p2) + b2[2];
    const float a3 = fmaf(wh2[3], h2, p3) + b2[3];
    const float c2n = fmaf(sigf(a1), c2, sigf(a0) * tanhfast(a2));
    const float h2n = sigf(a3) * tanhfast(c2n);
    if (lane == 0) { c2h2[0] = c2n; c2h2[1] = h2n; *out_ptr = h2n; }
}

__global__ __launch_bounds__(256, 4)
void lstm2_fused(const float* __restrict__ stim,
                 const float* __restrict__ Wih1,
                 const float* __restrict__ Whh1,
                 const float* __restrict__ bih1,
                 const float* __restrict__ bhh1,
                 const float* __restrict__ Wih2,
                 const float* __restrict__ Whh2,
                 const float* __restrict__ bih2,
                 const float* __restrict__ bhh2,
                 float* __restrict__ out)
{
    const int n    = blockIdx.x;
    const int tid  = threadIdx.x;
    const int wid  = tid >> 6;
    const int lane = tid & 63;
    const int gate = lane & 3;                 // 0=i 1=f 2=g 3=o
    const int unit = wid * 16 + (lane >> 2);   // hidden unit, valid < 51
    const bool uval = (unit < H);

    __shared__ __align__(16) float xrow[TL];
    __shared__ __align__(16) float hbuf[2][56];   // 56: pad so both bufs 16B-aligned
    __shared__ float c2h2[2];

    // ---- stage stimulus row to LDS, coalesced float4 ----
    {
        const float4* s4 = reinterpret_cast<const float4*>(stim + (size_t)n * TL);
        float4* d4 = reinterpret_cast<float4*>(xrow);
        d4[tid]       = s4[tid];
        d4[tid + 256] = s4[tid + 256];
    }

    // ---- layer-1 weights into registers (one row per thread) ----
    float w[52];
    float bsum = 0.0f, wi1 = 0.0f;
    if (uval) {
        const int r = gate * H + unit;
        const float* wr = Whh1 + r * H;
        #pragma unroll
        for (int j = 0; j < H; ++j) w[j] = wr[j];
        bsum = bih1[r] + bhh1[r];
        wi1  = Wih1[r];
    } else {
        #pragma unroll
        for (int j = 0; j < H; ++j) w[j] = 0.0f;
    }
    w[51] = 0.0f;

    // ---- layer-2 weights (per-lane column + uniform scalars) ----
    float w2[4], wh2[4], b2[4];
    #pragma unroll
    for (int k = 0; k < 4; ++k) {
        w2[k]  = (lane < H) ? Wih2[k * H + lane] : 0.0f;
        wh2[k] = Whh2[k];
        b2[k]  = bih2[k] + bhh2[k];
    }

    if (tid < 56) { hbuf[0][tid] = 0.0f; hbuf[1][tid] = 0.0f; }
    if (tid == 0) { c2h2[0] = 0.0f; c2h2[1] = 0.0f; }
    __syncthreads();

    float c1 = 0.0f;
    float* out_row = out + (size_t)n * TL;
    const int rot = (n + (n >> 8)) & 3;   // decorrelate layer-2 wave across co-resident blocks

    for (int t = 0; t < TL; ++t) {
        const float* hprev = hbuf[(t & 1) ^ 1];   // h1(t-1)

        // ---- layer 2 for step t-1, one rotating wave (overlaps layer-1 below) ----
        if (t > 0 && wid == ((t + rot) & 3)) {
            layer2_step(hprev, lane, w2, wh2, b2, c2h2, out_row + (t - 1));
        }

        // ---- layer 1: gate pre-activations (52 reg-FMAs, LDS b128 broadcasts) ----
        const float x = xrow[t];
        float a0 = fmaf(x, wi1, bsum), a1 = 0.0f, a2 = 0.0f, a3 = 0.0f;
        const float4* h4 = reinterpret_cast<const float4*>(hprev);
        #pragma unroll
        for (int j4 = 0; j4 < 13; ++j4) {
            const float4 hv = h4[j4];
            a0 = fmaf(w[j4 * 4 + 0], hv.x, a0);
            a1 = fmaf(w[j4 * 4 + 1], hv.y, a1);
            a2 = fmaf(w[j4 * 4 + 2], hv.z, a2);
            a3 = fmaf(w[j4 * 4 + 3], hv.w, a3);
        }
        const float a = (a0 + a1) + (a2 + a3);

        // activation: tanh for gate 2, sigmoid otherwise (branchless)
        const bool istanh = (gate == 2);
        const float s  = istanh ? (a + a) : a;
        const float sg = sigf(s);
        const float v  = istanh ? fmaf(2.0f, sg, -1.0f) : sg;

        // gather the quad's 4 gates via DPP (no LDS, no barrier)
        const float vi = quadb<0x00>(v);
        const float vf = quadb<0x55>(v);
        const float vg = quadb<0xAA>(v);
        const float vo = quadb<0xFF>(v);

        c1 = fmaf(vf, c1, vi * vg);
        const float h1 = vo * tanhfast(c1);
        if (uval && gate == 0) hbuf[t & 1][unit] = h1;

        __syncthreads();   // the single per-step barrier
    }

    // ---- drain: layer 2 for t = TL-1 ----
    if (wid == ((TL + rot) & 3)) {
        layer2_step(hbuf[(TL & 1) ^ 1], lane, w2, wh2, b2, c2h2, out_row + (TL - 1));
    }
}

extern "C" void kernel_launch(void* const* d_in, const int* in_sizes, int n_in,
                              void* d_out, int out_size, void* d_ws, size_t ws_size,
                              hipStream_t stream) {
    const float* stim = (const float*)d_in[0];
    const float* Wih1 = (const float*)d_in[1];
    const float* Whh1 = (const float*)d_in[2];
    const float* bih1 = (const float*)d_in[3];
    const float* bhh1 = (const float*)d_in[4];
    const float* Wih2 = (const float*)d_in[5];
    const float* Whh2 = (const float*)d_in[6];
    const float* bih2 = (const float*)d_in[7];
    const float* bhh2 = (const float*)d_in[8];
    float* out = (float*)d_out;

    const int N = in_sizes[0] / TL;   // 1024
    lstm2_fused<<<dim3(N), dim3(256), 0, stream>>>(
        stim, Wih1, Whh1, bih1, bhh1, Wih2, Whh2, bih2, bhh2, out);
}